// Round 9
// baseline (22877.473 us; speedup 1.0000x reference)
//
#include <hip/hip_runtime.h>
#include <math.h>

namespace {
constexpr int L_ = 4, H_ = 4, D_ = 128, DFF_ = 512, T_ = 64, B_ = 1024;
constexpr int S_ = 4, BOS_ = 4, DH_ = 32;
constexpr int NB = 4;                 // batch elements per block
constexpr int NBLK = B_ / NB;         // 256 blocks = 1 per CU
constexpr int NTH = 1024;             // 16 waves: wave = (e, h)

// workspace: KV cache only (exactly 256 MiB), head-major
constexpr size_t KC_BLK = (size_t)L_ * NB * H_ * T_ * DH_;   // 131072 floats
constexpr size_t VC_OFF = (size_t)NBLK * KC_BLK;
}

__device__ __forceinline__ float4 ld4(const float* p) {
  return *reinterpret_cast<const float4*>(p);
}

__device__ __forceinline__ float gelu_exact(float v) {
  return 0.5f * v * (1.0f + erff(v * 0.70710678118654752440f));
}

#define SEL4(a, e) ((e) == 0 ? (a)[0] : (e) == 1 ? (a)[1] : (e) == 2 ? (a)[2] : (a)[3])

// per-element-group (4 waves) spin barrier on LDS counter
__device__ __forceinline__ void gbar(int* cnt, int lane) {
  int tgt = 0;
  if (lane == 0) {
    int my = __hip_atomic_fetch_add(cnt, 1, __ATOMIC_RELEASE,
                                    __HIP_MEMORY_SCOPE_WORKGROUP);
    tgt = (my & ~3) + 4;
  }
  tgt = __shfl(tgt, 0);
  while (__hip_atomic_load(cnt, __ATOMIC_ACQUIRE,
                           __HIP_MEMORY_SCOPE_WORKGROUP) < tgt) {
    __builtin_amdgcn_s_sleep(1);
  }
}

// redundant per-wave LN: wave reads full src, writes full dst (identical values
// across the group's waves -> benign write races, no barrier needed)
__device__ __forceinline__ void ln_red(const float* __restrict__ src,
                                       float* __restrict__ dst,
                                       const float* __restrict__ w,
                                       const float* __restrict__ b, int lane) {
  float v0 = src[lane], v1 = src[lane + 64];
  float s = v0 + v1;
#pragma unroll
  for (int off = 32; off > 0; off >>= 1) s += __shfl_xor(s, off);
  float mu = s * (1.f / 128.f);
  float d0 = v0 - mu, d1 = v1 - mu;
  float s2 = d0 * d0 + d1 * d1;
#pragma unroll
  for (int off = 32; off > 0; off >>= 1) s2 += __shfl_xor(s2, off);
  float inv = 1.f / sqrtf(s2 * (1.f / 128.f) + 1e-5f);
  dst[lane] = d0 * inv * w[lane] + b[lane];
  dst[lane + 64] = d1 * inv * w[lane + 64] + b[lane + 64];
}

__global__ __launch_bounds__(NTH) void decode_kernel(
    const float* __restrict__ gumbel, const float* __restrict__ state_emb,
    const float* __restrict__ pos_emb,
    const float* __restrict__ ln1w, const float* __restrict__ ln1b,
    const float* __restrict__ wqkv, const float* __restrict__ bqkv,
    const float* __restrict__ wo, const float* __restrict__ bo,
    const float* __restrict__ ln2w, const float* __restrict__ ln2b,
    const float* __restrict__ w1, const float* __restrict__ b1,
    const float* __restrict__ w2, const float* __restrict__ b2,
    const float* __restrict__ fnw, const float* __restrict__ fnb,
    const float* __restrict__ headw, const float* __restrict__ headb,
    const int* __restrict__ nalpha, const int* __restrict__ nbeta,
    float* __restrict__ ws, float* __restrict__ out) {
  const int tid = threadIdx.x;
  const int blk = blockIdx.x;
  const int lane = tid & 63;
  const int w = tid >> 6;         // wave 0..15
  const int e = w >> 2;           // element 0..3
  const int h = w & 3;            // head 0..3
  const int og8 = lane >> 3;      // row slot 0..7
  const int k8 = lane & 7;        // k-slice 0..7 (16 floats interleaved)

  float* Kc = ws + (size_t)blk * KC_BLK;
  float* Vc = ws + VC_OFF + (size_t)blk * KC_BLK;

  __shared__ __align__(16) float xres[NB][D_];
  __shared__ __align__(16) float xn[NB][D_];
  __shared__ __align__(16) float ctx[NB][D_];
  __shared__ __align__(16) float hbuf[NB][DFF_];
  __shared__ __align__(16) float qs[NB][H_][DH_];
  __shared__ float ps[NB][H_][T_];
  __shared__ float logits[NB][S_];
  __shared__ int cnt[NB];

  int bs_cur = BOS_;
  int arem_r = nalpha[0], brem_r = nbeta[0];
  float lps_r = 0.f;
  if (tid < NB) cnt[tid] = 0;
  __syncthreads();

  for (int i = 0; i < T_; ++i) {
    // ---- embed: wave (e,h) writes its 32-slice of xres[e]
    if (lane < 32) {
      const int d = h * 32 + lane;
      xres[e][d] = state_emb[bs_cur * D_ + d] + pos_emb[i * D_ + d];
    }
    gbar(&cnt[e], lane);

    for (int l = 0; l < L_; ++l) {
      // ---- LN1 (redundant per wave, no barrier)
      ln_red(xres[e], xn[e], ln1w + l * D_, ln1b + l * D_, lane);

      // ---- QKV for own head: q rows -> qs, k/v rows -> private cache slice
      {
        const float* wq = wqkv + ((size_t)l * 384 + h * 32) * D_;
        const float* wk = wqkv + ((size_t)l * 384 + 128 + h * 32) * D_;
        const float* wv = wqkv + ((size_t)l * 384 + 256 + h * 32) * D_;
        const size_t cb = (((size_t)(l * NB + e) * H_ + h) * T_ + i) * DH_;
#pragma unroll
        for (int rg = 0; rg < 4; ++rg) {
          const int r = rg * 8 + og8;
          const float* wr = wq + (size_t)r * D_;
          float acc = 0.f;
#pragma unroll
          for (int m = 0; m < 4; ++m) {
            const int f4 = k8 + 8 * m;
            const float4 w4 = ld4(wr + 4 * f4);
            const float4 x4 = ld4(&xn[e][4 * f4]);
            acc += w4.x * x4.x + w4.y * x4.y + w4.z * x4.z + w4.w * x4.w;
          }
          acc += __shfl_xor(acc, 1); acc += __shfl_xor(acc, 2); acc += __shfl_xor(acc, 4);
          if (k8 == 0) qs[e][h][r] = acc + bqkv[l * 384 + h * 32 + r];
        }
#pragma unroll
        for (int rg = 0; rg < 4; ++rg) {
          const int r = rg * 8 + og8;
          const float* wr = wk + (size_t)r * D_;
          float acc = 0.f;
#pragma unroll
          for (int m = 0; m < 4; ++m) {
            const int f4 = k8 + 8 * m;
            const float4 w4 = ld4(wr + 4 * f4);
            const float4 x4 = ld4(&xn[e][4 * f4]);
            acc += w4.x * x4.x + w4.y * x4.y + w4.z * x4.z + w4.w * x4.w;
          }
          acc += __shfl_xor(acc, 1); acc += __shfl_xor(acc, 2); acc += __shfl_xor(acc, 4);
          if (k8 == 0) Kc[cb + r] = acc + bqkv[l * 384 + 128 + h * 32 + r];
        }
#pragma unroll
        for (int rg = 0; rg < 4; ++rg) {
          const int r = rg * 8 + og8;
          const float* wr = wv + (size_t)r * D_;
          float acc = 0.f;
#pragma unroll
          for (int m = 0; m < 4; ++m) {
            const int f4 = k8 + 8 * m;
            const float4 w4 = ld4(wr + 4 * f4);
            const float4 x4 = ld4(&xn[e][4 * f4]);
            acc += w4.x * x4.x + w4.y * x4.y + w4.z * x4.z + w4.w * x4.w;
          }
          acc += __shfl_xor(acc, 1); acc += __shfl_xor(acc, 2); acc += __shfl_xor(acc, 4);
          if (k8 == 0) Vc[cb + r] = acc + bqkv[l * 384 + 256 + h * 32 + r];
        }
      }
      // own-wave global RAW fence: K/V row i must land before we read it
      asm volatile("s_waitcnt vmcnt(0)" ::: "memory");

      // ---- attention (own head, zero barriers): scores+softmax+PV
      {
        const int t = lane;
        float s0 = -INFINITY;
        if (t <= i) {
          const float* kp = Kc + (((size_t)(l * NB + e) * H_ + h) * T_ + t) * DH_;
          float a = 0.f;
#pragma unroll
          for (int k = 0; k < 8; ++k) {
            const float4 qv = ld4(&qs[e][h][4 * k]);
            const float4 kv = ld4(kp + 4 * k);
            a += qv.x * kv.x + qv.y * kv.y + qv.z * kv.z + qv.w * kv.w;
          }
          s0 = a * 0.17677669529663687f;
        }
        float mx = s0;
#pragma unroll
        for (int off = 32; off > 0; off >>= 1) mx = fmaxf(mx, __shfl_xor(mx, off));
        float p = expf(s0 - mx);                 // 0 for t>i
        float sum = p;
#pragma unroll
        for (int off = 32; off > 0; off >>= 1) sum += __shfl_xor(sum, off);
        ps[e][h][t] = p / sum;

        const int j = lane & 31, thalf = lane >> 5;
        const float* vp = Vc + (((size_t)(l * NB + e) * H_ + h) * T_) * DH_ + j;
        const float* pp = &ps[e][h][thalf * 32];
        float acc = 0.f;
#pragma unroll
        for (int m = 0; m < 32; ++m) {
          if (thalf * 32 + m <= i) acc += pp[m] * vp[(size_t)(thalf * 32 + m) * DH_];
        }
        acc += __shfl_xor(acc, 32);
        if (thalf == 0) ctx[e][h * 32 + j] = acc;
      }
      gbar(&cnt[e], lane);   // ctx complete across heads

      // ---- wo: rows h*32..h*32+31, k = full 128 (reads full ctx)
#pragma unroll
      for (int rg = 0; rg < 4; ++rg) {
        const int r = h * 32 + rg * 8 + og8;
        const float* wr = wo + ((size_t)l * D_ + r) * D_;
        float acc = 0.f;
#pragma unroll
        for (int m = 0; m < 4; ++m) {
          const int f4 = k8 + 8 * m;
          const float4 w4 = ld4(wr + 4 * f4);
          const float4 x4 = ld4(&ctx[e][4 * f4]);
          acc += w4.x * x4.x + w4.y * x4.y + w4.z * x4.z + w4.w * x4.w;
        }
        acc += __shfl_xor(acc, 1); acc += __shfl_xor(acc, 2); acc += __shfl_xor(acc, 4);
        if (k8 == 0) xres[e][r] += acc + bo[l * D_ + r];
      }
      gbar(&cnt[e], lane);   // xres complete

      // ---- LN2 (redundant)
      ln_red(xres[e], xn[e], ln2w + l * D_, ln2b + l * D_, lane);

      // ---- FFN1 + GELU: rows h*128..h*128+127
#pragma unroll 4
      for (int rg = 0; rg < 16; ++rg) {
        const int r = h * 128 + rg * 8 + og8;
        const float* wr = w1 + ((size_t)l * DFF_ + r) * D_;
        float acc = 0.f;
#pragma unroll
        for (int m = 0; m < 4; ++m) {
          const int f4 = k8 + 8 * m;
          const float4 w4 = ld4(wr + 4 * f4);
          const float4 x4 = ld4(&xn[e][4 * f4]);
          acc += w4.x * x4.x + w4.y * x4.y + w4.z * x4.z + w4.w * x4.w;
        }
        acc += __shfl_xor(acc, 1); acc += __shfl_xor(acc, 2); acc += __shfl_xor(acc, 4);
        if (k8 == 0) hbuf[e][r] = gelu_exact(acc + b1[l * DFF_ + r]);
      }
      gbar(&cnt[e], lane);   // hbuf complete

      // ---- FFN2: rows h*32..h*32+31, k = full 512
#pragma unroll
      for (int rg = 0; rg < 4; ++rg) {
        const int r = h * 32 + rg * 8 + og8;
        const float* wr = w2 + ((size_t)l * D_ + r) * DFF_;
        float acc = 0.f;
#pragma unroll
        for (int m = 0; m < 16; ++m) {
          const int f4 = k8 + 8 * m;
          const float4 w4 = ld4(wr + 4 * f4);
          const float4 x4 = ld4(&hbuf[e][4 * f4]);
          acc += w4.x * x4.x + w4.y * x4.y + w4.z * x4.z + w4.w * x4.w;
        }
        acc += __shfl_xor(acc, 1); acc += __shfl_xor(acc, 2); acc += __shfl_xor(acc, 4);
        if (k8 == 0) xres[e][r] += acc + b2[l * D_ + r];
      }
      gbar(&cnt[e], lane);   // xres complete for next layer
    }  // layers

    // ---- final LN (redundant)
    ln_red(xres[e], xn[e], fnw, fnb, lane);

    // ---- head: wave (e,h) computes logits[e][h]
    {
      float v = xn[e][lane] * headw[h * D_ + lane] +
                xn[e][lane + 64] * headw[h * D_ + lane + 64];
#pragma unroll
      for (int off = 32; off > 0; off >>= 1) v += __shfl_xor(v, off);
      if (lane == 0) logits[e][h] = v + headb[h];
    }
    gbar(&cnt[e], lane);   // logits complete

    // ---- sample (redundant in every lane of the group; identical results)
    {
      const int a = arem_r, bb = brem_r;
      const int oa = T_ - 1 - i;
      bool mk[4];
      mk[0] = (a <= oa) && (bb <= oa);
      mk[1] = (bb > 0) && (a <= oa) && (bb - 1 <= oa);
      mk[2] = (a > 0) && (a - 1 <= oa) && (bb <= oa);
      mk[3] = (a > 0) && (bb > 0) && (a - 1 <= oa) && (bb - 1 <= oa);
      float mx = -INFINITY;
#pragma unroll
      for (int s = 0; s < 4; ++s)
        if (mk[s]) mx = fmaxf(mx, logits[e][s]);
      float sum = 0.f;
      float lg[4];
#pragma unroll
      for (int s = 0; s < 4; ++s) {
        if (mk[s]) {
          const float z = logits[e][s] - mx;
          sum += expf(z);
          lg[s] = z;
        } else {
          lg[s] = -INFINITY;
        }
      }
      const float lse = logf(sum);
      const size_t gb = ((size_t)(blk * NB + e) * T_ + i) * S_;
      float best = -INFINITY;
      int bs = 0;
#pragma unroll
      for (int s = 0; s < 4; ++s) {
        const float y = (lg[s] - lse) + gumbel[gb + s];
        if (y > best) { best = y; bs = s; }
      }
      lps_r += SEL4(lg, bs) - lse;
      if (w == e * 4 && lane == 0) out[(size_t)(blk * NB + e) * T_ + i] = (float)bs;
      bs_cur = bs;
      arem_r = a - (bs >> 1);
      brem_r = bb - (bs & 1);
    }
    // no barrier: embed (next i) writes xres only after this group's waves
    // passed the logits barrier, i.e. after all xres reads of this step.
  }  // steps

  if (h == 0 && lane == 0) out[(size_t)B_ * T_ + blk * NB + e] = lps_r;
}

extern "C" void kernel_launch(void* const* d_in, const int* in_sizes, int n_in,
                              void* d_out, int out_size, void* d_ws, size_t ws_size,
                              hipStream_t stream) {
  const float* gumbel    = (const float*)d_in[0];
  const float* state_emb = (const float*)d_in[1];
  const float* pos_emb   = (const float*)d_in[2];
  const float* ln1w      = (const float*)d_in[3];
  const float* ln1b      = (const float*)d_in[4];
  const float* wqkv      = (const float*)d_in[5];
  const float* bqkv      = (const float*)d_in[6];
  const float* wo        = (const float*)d_in[7];
  const float* bo        = (const float*)d_in[8];
  const float* ln2w      = (const float*)d_in[9];
  const float* ln2b      = (const float*)d_in[10];
  const float* w1        = (const float*)d_in[11];
  const float* b1        = (const float*)d_in[12];
  const float* w2        = (const float*)d_in[13];
  const float* b2        = (const float*)d_in[14];
  const float* fnw       = (const float*)d_in[15];
  const float* fnb       = (const float*)d_in[16];
  const float* headw     = (const float*)d_in[17];
  const float* headb     = (const float*)d_in[18];
  const int* nalpha      = (const int*)d_in[19];
  const int* nbeta       = (const int*)d_in[20];
  float* ws = (float*)d_ws;
  float* out = (float*)d_out;

  decode_kernel<<<dim3(NBLK), dim3(NTH), 0, stream>>>(
      gumbel, state_emb, pos_emb, ln1w, ln1b, wqkv, bqkv, wo, bo, ln2w, ln2b,
      w1, b1, w2, b2, fnw, fnb, headw, headb, nalpha, nbeta, ws, out);
}

// Round 10
// 17551.064 us; speedup vs baseline: 1.3035x; 1.3035x over previous
//
#include <hip/hip_runtime.h>
#include <math.h>

namespace {
constexpr int L_ = 4, H_ = 4, D_ = 128, DFF_ = 512, T_ = 64, B_ = 1024;
constexpr int S_ = 4, BOS_ = 4, DH_ = 32;
constexpr int NB = 2;                 // batch elements per block
constexpr int NBLK = B_ / NB;         // 512 blocks = 2 per CU  (cross-block overlap)
constexpr int NTH = 512;              // 8 waves per block

// workspace: KV cache only (exactly 256 MiB)
constexpr size_t KC_BLK = (size_t)L_ * NB * T_ * D_;   // 65536 floats per block
constexpr size_t VC_OFF = (size_t)NBLK * KC_BLK;
}

__device__ __forceinline__ float4 ld4(const float* p) {
  return *reinterpret_cast<const float4*>(p);
}

__device__ __forceinline__ float gelu_exact(float v) {
  return 0.5f * v * (1.0f + erff(v * 0.70710678118654752440f));
}

// one wave normalizes one 128-vector: lane holds src[lane], src[lane+64]
__device__ __forceinline__ void ln_wave(const float* __restrict__ src,
                                        float* __restrict__ dst,
                                        const float* __restrict__ w,
                                        const float* __restrict__ b, int lane) {
  float v0 = src[lane], v1 = src[lane + 64];
  float s = v0 + v1;
#pragma unroll
  for (int off = 32; off > 0; off >>= 1) s += __shfl_xor(s, off);
  float mu = s * (1.f / 128.f);
  float d0 = v0 - mu, d1 = v1 - mu;
  float s2 = d0 * d0 + d1 * d1;
#pragma unroll
  for (int off = 32; off > 0; off >>= 1) s2 += __shfl_xor(s2, off);
  float inv = 1.f / sqrtf(s2 * (1.f / 128.f) + 1e-5f);
  dst[lane] = d0 * inv * w[lane] + b[lane];
  dst[lane + 64] = d1 * inv * w[lane + 64] + b[lane + 64];
}

// butterfly-reduce over the 8-lane k8 group (lanes are 8-aligned)
#define RED8(a) { a += __shfl_xor(a, 1); a += __shfl_xor(a, 2); a += __shfl_xor(a, 4); }

__global__ __launch_bounds__(NTH) void decode_kernel(
    const float* __restrict__ gumbel, const float* __restrict__ state_emb,
    const float* __restrict__ pos_emb,
    const float* __restrict__ ln1w, const float* __restrict__ ln1b,
    const float* __restrict__ wqkv, const float* __restrict__ bqkv,
    const float* __restrict__ wo, const float* __restrict__ bo,
    const float* __restrict__ ln2w, const float* __restrict__ ln2b,
    const float* __restrict__ w1, const float* __restrict__ b1,
    const float* __restrict__ w2, const float* __restrict__ b2,
    const float* __restrict__ fnw, const float* __restrict__ fnb,
    const float* __restrict__ headw, const float* __restrict__ headb,
    const int* __restrict__ nalpha, const int* __restrict__ nbeta,
    float* __restrict__ ws, float* __restrict__ out) {
  const int tid = threadIdx.x;
  const int blk = blockIdx.x;
  const int lane = tid & 63;
  const int w = tid >> 6;            // wave 0..7
  const int og = tid >> 3;           // 0..63 (output row group)
  const int k8 = tid & 7;            // 0..7  (interleaved k-slice)

  float* Kc = ws + (size_t)blk * KC_BLK;
  float* Vc = ws + VC_OFF + (size_t)blk * KC_BLK;

  __shared__ __align__(16) float xres[NB][D_];
  __shared__ __align__(16) float xn[NB][D_];
  __shared__ __align__(16) float qb[NB][D_];    // q, later ctx
  __shared__ __align__(16) float hbuf[NB][DFF_];
  __shared__ float ps[NB][H_][T_];              // softmax probs (0 for t>i)
  __shared__ float logits[NB][S_];
  __shared__ int tok[NB];

  int arem_r = 0, brem_r = 0;
  float lps_r = 0.f;
  if (tid < NB) {
    tok[tid] = BOS_;
    arem_r = nalpha[0];
    brem_r = nbeta[0];
  }
  __syncthreads();

  for (int i = 0; i < T_; ++i) {
    // ---- embed
    if (tid < NB * D_) {
      const int e = tid >> 7, d = tid & 127;
      xres[e][d] = state_emb[tok[e] * D_ + d] + pos_emb[i * D_ + d];
    }
    __syncthreads();

    for (int l = 0; l < L_; ++l) {
      // ---- LN1 (waves 0..1)
      if (w < NB) ln_wave(xres[w], xn[w], ln1w + l * D_, ln1b + l * D_, lane);
      __syncthreads();

      // ---- QKV: 6 rows/og (og+64p, p=0..5), x-slice shared across rows
      {
        float aq0[2] = {0.f, 0.f}, aq1[2] = {0.f, 0.f};
        float ak0[2] = {0.f, 0.f}, ak1[2] = {0.f, 0.f};
        float av0[2] = {0.f, 0.f}, av1[2] = {0.f, 0.f};
        const float* wb = wqkv + (size_t)l * 384 * D_;
#pragma unroll
        for (int m = 0; m < 4; ++m) {
          const int f4 = k8 + 8 * m;
          const float4 x0 = ld4(&xn[0][4 * f4]);
          const float4 x1 = ld4(&xn[1][4 * f4]);
          const float4 wq0 = ld4(wb + (size_t)(og) * D_ + 4 * f4);
          const float4 wq1 = ld4(wb + (size_t)(og + 64) * D_ + 4 * f4);
          const float4 wk0 = ld4(wb + (size_t)(og + 128) * D_ + 4 * f4);
          const float4 wk1 = ld4(wb + (size_t)(og + 192) * D_ + 4 * f4);
          const float4 wv0 = ld4(wb + (size_t)(og + 256) * D_ + 4 * f4);
          const float4 wv1 = ld4(wb + (size_t)(og + 320) * D_ + 4 * f4);
          aq0[0] += wq0.x * x0.x + wq0.y * x0.y + wq0.z * x0.z + wq0.w * x0.w;
          aq0[1] += wq0.x * x1.x + wq0.y * x1.y + wq0.z * x1.z + wq0.w * x1.w;
          aq1[0] += wq1.x * x0.x + wq1.y * x0.y + wq1.z * x0.z + wq1.w * x0.w;
          aq1[1] += wq1.x * x1.x + wq1.y * x1.y + wq1.z * x1.z + wq1.w * x1.w;
          ak0[0] += wk0.x * x0.x + wk0.y * x0.y + wk0.z * x0.z + wk0.w * x0.w;
          ak0[1] += wk0.x * x1.x + wk0.y * x1.y + wk0.z * x1.z + wk0.w * x1.w;
          ak1[0] += wk1.x * x0.x + wk1.y * x0.y + wk1.z * x0.z + wk1.w * x0.w;
          ak1[1] += wk1.x * x1.x + wk1.y * x1.y + wk1.z * x1.z + wk1.w * x1.w;
          av0[0] += wv0.x * x0.x + wv0.y * x0.y + wv0.z * x0.z + wv0.w * x0.w;
          av0[1] += wv0.x * x1.x + wv0.y * x1.y + wv0.z * x1.z + wv0.w * x1.w;
          av1[0] += wv1.x * x0.x + wv1.y * x0.y + wv1.z * x0.z + wv1.w * x0.w;
          av1[1] += wv1.x * x1.x + wv1.y * x1.y + wv1.z * x1.z + wv1.w * x1.w;
        }
        RED8(aq0[0]); RED8(aq0[1]); RED8(aq1[0]); RED8(aq1[1]);
        RED8(ak0[0]); RED8(ak0[1]); RED8(ak1[0]); RED8(ak1[1]);
        RED8(av0[0]); RED8(av0[1]); RED8(av1[0]); RED8(av1[1]);
        const float* bq = bqkv + l * 384;
        if (k8 == 0) {
          const size_t cb = (((size_t)l * NB + 0) * T_ + i) * D_;
          qb[0][og] = aq0[0] + bq[og];
          qb[0][og + 64] = aq1[0] + bq[og + 64];
          Kc[cb + og] = ak0[0] + bq[og + 128];
          Kc[cb + og + 64] = ak1[0] + bq[og + 192];
          Vc[cb + og] = av0[0] + bq[og + 256];
          Vc[cb + og + 64] = av1[0] + bq[og + 320];
        } else if (k8 == 1) {
          const size_t cb = (((size_t)l * NB + 1) * T_ + i) * D_;
          qb[1][og] = aq0[1] + bq[og];
          qb[1][og + 64] = aq1[1] + bq[og + 64];
          Kc[cb + og] = ak0[1] + bq[og + 128];
          Kc[cb + og + 64] = ak1[1] + bq[og + 192];
          Vc[cb + og] = av0[1] + bq[og + 256];
          Vc[cb + og + 64] = av1[1] + bq[og + 320];
        }
      }
      __syncthreads();

      // ---- attention: wave = (e,h); scores + softmax + PV
      {
        const int e = w >> 2, h = w & 3;
        const int t = lane;
        float s0 = -INFINITY;
        if (t <= i) {
          const float4* q4 = reinterpret_cast<const float4*>(&qb[e][h * DH_]);
          const float* kp = Kc + (((size_t)l * NB + e) * T_ + t) * D_ + h * DH_;
          float a = 0.f;
#pragma unroll
          for (int k = 0; k < 8; ++k) {
            const float4 qv = q4[k];
            const float4 kv = ld4(kp + 4 * k);
            a += qv.x * kv.x + qv.y * kv.y + qv.z * kv.z + qv.w * kv.w;
          }
          s0 = a * 0.17677669529663687f;
        }
        float mx = s0;
#pragma unroll
        for (int off = 32; off > 0; off >>= 1) mx = fmaxf(mx, __shfl_xor(mx, off));
        float p = expf(s0 - mx);                 // 0 for t>i
        float sum = p;
#pragma unroll
        for (int off = 32; off > 0; off >>= 1) sum += __shfl_xor(sum, off);
        ps[e][h][t] = p / sum;

        const int j = lane & 31, thalf = lane >> 5;
        const float* vp = Vc + (((size_t)l * NB + e) * T_ + thalf * 32) * D_ + h * DH_ + j;
        const float* pp = &ps[e][h][thalf * 32];
        float acc = 0.f;
#pragma unroll
        for (int m = 0; m < 32; ++m) {
          if (thalf * 32 + m <= i) acc += pp[m] * vp[(size_t)m * D_];
        }
        acc += __shfl_xor(acc, 32);
        if (thalf == 0) qb[e][h * DH_ + j] = acc;
      }
      __syncthreads();

      // ---- wo: 2 rows/og, x = ctx (qb)
      {
        float a0[2] = {0.f, 0.f}, a1[2] = {0.f, 0.f};
        const float* wb = wo + (size_t)l * D_ * D_;
#pragma unroll
        for (int m = 0; m < 4; ++m) {
          const int f4 = k8 + 8 * m;
          const float4 x0 = ld4(&qb[0][4 * f4]);
          const float4 x1 = ld4(&qb[1][4 * f4]);
          const float4 w0 = ld4(wb + (size_t)(og) * D_ + 4 * f4);
          const float4 w1v = ld4(wb + (size_t)(og + 64) * D_ + 4 * f4);
          a0[0] += w0.x * x0.x + w0.y * x0.y + w0.z * x0.z + w0.w * x0.w;
          a0[1] += w0.x * x1.x + w0.y * x1.y + w0.z * x1.z + w0.w * x1.w;
          a1[0] += w1v.x * x0.x + w1v.y * x0.y + w1v.z * x0.z + w1v.w * x0.w;
          a1[1] += w1v.x * x1.x + w1v.y * x1.y + w1v.z * x1.z + w1v.w * x1.w;
        }
        RED8(a0[0]); RED8(a0[1]); RED8(a1[0]); RED8(a1[1]);
        if (k8 == 0) {
          xres[0][og] += a0[0] + bo[l * D_ + og];
          xres[0][og + 64] += a1[0] + bo[l * D_ + og + 64];
        } else if (k8 == 1) {
          xres[1][og] += a0[1] + bo[l * D_ + og];
          xres[1][og + 64] += a1[1] + bo[l * D_ + og + 64];
        }
      }
      __syncthreads();

      // ---- LN2
      if (w < NB) ln_wave(xres[w], xn[w], ln2w + l * D_, ln2b + l * D_, lane);
      __syncthreads();

      // ---- FFN1 + GELU: 8 rows/og (og+64p), x-slice shared
      {
        float ac[8][2];
#pragma unroll
        for (int r = 0; r < 8; ++r) { ac[r][0] = 0.f; ac[r][1] = 0.f; }
        const float* wb = w1 + (size_t)l * DFF_ * D_;
#pragma unroll
        for (int m = 0; m < 4; ++m) {
          const int f4 = k8 + 8 * m;
          const float4 x0 = ld4(&xn[0][4 * f4]);
          const float4 x1 = ld4(&xn[1][4 * f4]);
#pragma unroll
          for (int r = 0; r < 8; ++r) {
            const float4 w4 = ld4(wb + (size_t)(og + 64 * r) * D_ + 4 * f4);
            ac[r][0] += w4.x * x0.x + w4.y * x0.y + w4.z * x0.z + w4.w * x0.w;
            ac[r][1] += w4.x * x1.x + w4.y * x1.y + w4.z * x1.z + w4.w * x1.w;
          }
        }
#pragma unroll
        for (int r = 0; r < 8; ++r) { RED8(ac[r][0]); RED8(ac[r][1]); }
        if (k8 == 0) {
#pragma unroll
          for (int r = 0; r < 8; ++r) {
            const int o = og + 64 * r;
            hbuf[0][o] = gelu_exact(ac[r][0] + b1[l * DFF_ + o]);
          }
        } else if (k8 == 1) {
#pragma unroll
          for (int r = 0; r < 8; ++r) {
            const int o = og + 64 * r;
            hbuf[1][o] = gelu_exact(ac[r][1] + b1[l * DFF_ + o]);
          }
        }
      }
      __syncthreads();

      // ---- FFN2: 2 rows/og, k over 512 (h-slice shared across rows)
      {
        float a0[2] = {0.f, 0.f}, a1[2] = {0.f, 0.f};
        const float* wb = w2 + (size_t)l * D_ * DFF_;
#pragma unroll
        for (int m = 0; m < 16; ++m) {
          const int f4 = k8 + 8 * m;
          const float4 h0 = ld4(&hbuf[0][4 * f4]);
          const float4 h1 = ld4(&hbuf[1][4 * f4]);
          const float4 w0 = ld4(wb + (size_t)(og) * DFF_ + 4 * f4);
          const float4 w1v = ld4(wb + (size_t)(og + 64) * DFF_ + 4 * f4);
          a0[0] += w0.x * h0.x + w0.y * h0.y + w0.z * h0.z + w0.w * h0.w;
          a0[1] += w0.x * h1.x + w0.y * h1.y + w0.z * h1.z + w0.w * h1.w;
          a1[0] += w1v.x * h0.x + w1v.y * h0.y + w1v.z * h0.z + w1v.w * h0.w;
          a1[1] += w1v.x * h1.x + w1v.y * h1.y + w1v.z * h1.z + w1v.w * h1.w;
        }
        RED8(a0[0]); RED8(a0[1]); RED8(a1[0]); RED8(a1[1]);
        if (k8 == 0) {
          xres[0][og] += a0[0] + b2[l * D_ + og];
          xres[0][og + 64] += a1[0] + b2[l * D_ + og + 64];
        } else if (k8 == 1) {
          xres[1][og] += a0[1] + b2[l * D_ + og];
          xres[1][og + 64] += a1[1] + b2[l * D_ + og + 64];
        }
      }
      __syncthreads();
    }  // layers

    // ---- final LN
    if (w < NB) ln_wave(xres[w], xn[w], fnw, fnb, lane);
    __syncthreads();

    // ---- head: 256 threads: (e, s, j)
    if (tid < 256) {
      const int e = tid >> 7, rest = tid & 127, s = rest >> 5, j = rest & 31;
      const float4 a = ld4(&xn[e][4 * j]);
      const float4 hw = ld4(headw + s * D_ + 4 * j);
      float acc = a.x * hw.x + a.y * hw.y + a.z * hw.z + a.w * hw.w;
#pragma unroll
      for (int off = 1; off < 32; off <<= 1) acc += __shfl_xor(acc, off);
      if (j == 0) logits[e][s] = acc + headb[s];
    }
    __syncthreads();

    // ---- mask + log-softmax + gumbel-argmax (threads 0..1)
    if (tid < NB) {
      const int e = tid;
      const int b = blk * NB + e;
      const int a = arem_r, bb = brem_r;
      const int oa = T_ - 1 - i;
      bool mk[4];
      mk[0] = (a <= oa) && (bb <= oa);
      mk[1] = (bb > 0) && (a <= oa) && (bb - 1 <= oa);
      mk[2] = (a > 0) && (a - 1 <= oa) && (bb <= oa);
      mk[3] = (a > 0) && (bb > 0) && (a - 1 <= oa) && (bb - 1 <= oa);
      float mx = -INFINITY;
#pragma unroll
      for (int s = 0; s < 4; ++s)
        if (mk[s]) mx = fmaxf(mx, logits[e][s]);
      float sum = 0.f;
      float lg[4];
#pragma unroll
      for (int s = 0; s < 4; ++s) {
        if (mk[s]) {
          const float z = logits[e][s] - mx;
          sum += expf(z);
          lg[s] = z;
        } else {
          lg[s] = -INFINITY;
        }
      }
      const float lse = logf(sum);
      float best = -INFINITY;
      int bs = 0;
#pragma unroll
      for (int s = 0; s < 4; ++s) {
        const float y = (lg[s] - lse) + gumbel[((size_t)b * T_ + i) * S_ + s];
        if (y > best) { best = y; bs = s; }
      }
      lps_r += ((bs == 0) ? lg[0] : (bs == 1) ? lg[1] : (bs == 2) ? lg[2] : lg[3]) - lse;
      out[(size_t)b * T_ + i] = (float)bs;
      tok[e] = bs;
      arem_r = a - (bs >> 1);
      brem_r = bb - (bs & 1);
    }
    __syncthreads();
  }  // steps

  if (tid < NB) out[(size_t)B_ * T_ + blk * NB + tid] = lps_r;
}

extern "C" void kernel_launch(void* const* d_in, const int* in_sizes, int n_in,
                              void* d_out, int out_size, void* d_ws, size_t ws_size,
                              hipStream_t stream) {
  const float* gumbel    = (const float*)d_in[0];
  const float* state_emb = (const float*)d_in[1];
  const float* pos_emb   = (const float*)d_in[2];
  const float* ln1w      = (const float*)d_in[3];
  const float* ln1b      = (const float*)d_in[4];
  const float* wqkv      = (const float*)d_in[5];
  const float* bqkv      = (const float*)d_in[6];
  const float* wo        = (const float*)d_in[7];
  const float* bo        = (const float*)d_in[8];
  const float* ln2w      = (const float*)d_in[9];
  const float* ln2b      = (const float*)d_in[10];
  const float* w1        = (const float*)d_in[11];
  const float* b1        = (const float*)d_in[12];
  const float* w2        = (const float*)d_in[13];
  const float* b2        = (const float*)d_in[14];
  const float* fnw       = (const float*)d_in[15];
  const float* fnb       = (const float*)d_in[16];
  const float* headw     = (const float*)d_in[17];
  const float* headb     = (const float*)d_in[18];
  const int* nalpha      = (const int*)d_in[19];
  const int* nbeta       = (const int*)d_in[20];
  float* ws = (float*)d_ws;
  float* out = (float*)d_out;

  decode_kernel<<<dim3(NBLK), dim3(NTH), 0, stream>>>(
      gumbel, state_emb, pos_emb, ln1w, ln1b, wqkv, bqkv, wo, bo, ln2w, ln2b,
      w1, b1, w2, b2, fnw, fnb, headw, headb, nalpha, nbeta, ws, out);
}